// Round 5
// baseline (318.355 us; speedup 1.0000x reference)
//
#include <hip/hip_runtime.h>
#include <hip/hip_bf16.h>

// SGNHeadLSS — round 5: latency-exposure fixes on the r4 MFMA kernel.
// r4 post-mortem: all pipes idle (Mfma 3.3%, VALU 11%, HBM 18%, occ 40%)
// -> latency/issue-bound. Two changes:
//  (1) __launch_bounds__(256,6): VGPR cap 85 so 6 waves/SIMD are possible;
//      LDS (27.1 KB) allows 6 blocks/CU — make the RA budget match.
//  (2) gather hoist: issue all 32 scattered x3d loads before any bf16
//      packing (previous code packed every 8 -> 4 serialized ~900cyc rounds).
//      Per-channel bases are wave-uniform (SGPR), lane offset n_r*4 shared.
// Everything else byte-identical to the r4 kernel (passed, absmax 0.023).

#define NVOX 262144
#define NU   65536
#define NM   196608
#define CIN  128
#define CHALF 64
#define NCLS 20
#define TR   64
#define NBLK_M (NM / TR) // 3072
#define NBLK_U (NU / TR) // 1024

#define SXS 136   // sX row stride in bf16 (272B, 16B-aligned)
#define SHS 72    // sH row stride in bf16 (144B, 16B-aligned)

// ws layout (u16 units)
#define W1T_OFF  0       // [64][128]   w1^T
#define W2T_OFF  8192    // [128][64]   w2^T
#define SDBT_OFF 16384   // [64][128]   sdb_w^T
#define SSCT_OFF 24576   // [32][64]    ssc_w^T (rows 20..31 zero)
#define AUXT_OFF 26624   // [32][128]   aux_w^T (rows 20..31 zero)
#define WS_TOT   30720   // 61440 bytes

typedef unsigned short u16;
typedef short    bf16x8 __attribute__((ext_vector_type(8)));
typedef float    f32x4  __attribute__((ext_vector_type(4)));

__device__ __forceinline__ u16 f2b(float f) {
    __hip_bfloat16 h = __float2bfloat16(f);
    return *(u16*)&h;
}
__device__ __forceinline__ void wave_sync() {
    __asm__ volatile("s_waitcnt lgkmcnt(0)" ::: "memory");
}

__global__ void prep_weights(const float* __restrict__ w1,  const float* __restrict__ w2,
                             const float* __restrict__ sdbw,const float* __restrict__ sscw,
                             const float* __restrict__ auxw,u16* __restrict__ ws) {
    int i = blockIdx.x * blockDim.x + threadIdx.x;
    const int stride = gridDim.x * blockDim.x;
    for (; i < WS_TOT; i += stride) {
        float v;
        if (i < W2T_OFF)        { int n = i >> 7, k = i & 127;              v = w1[k*CHALF + n]; }
        else if (i < SDBT_OFF)  { int j = i - W2T_OFF;  int n = j >> 6, k = j & 63;
                                  v = w2[k*CIN + n]; }
        else if (i < SSCT_OFF)  { int j = i - SDBT_OFF; int n = j >> 7, k = j & 127;
                                  v = sdbw[k*CHALF + n]; }
        else if (i < AUXT_OFF)  { int j = i - SSCT_OFF; int n = j >> 6, k = j & 63;
                                  v = (n < NCLS) ? sscw[k*NCLS + n] : 0.f; }
        else                    { int j = i - AUXT_OFF; int n = j >> 7, k = j & 127;
                                  v = (n < NCLS) ? auxw[k*NCLS + n] : 0.f; }
        ws[i] = f2b(v);
    }
}

__global__ __launch_bounds__(256, 6)
void sgn_mfma(const float* __restrict__ x3d,
              const float* __restrict__ b1,   const float* __restrict__ lng,
              const float* __restrict__ lnb,  const float* __restrict__ bb2,
              const float* __restrict__ sdbb, const float* __restrict__ sscb,
              const float* __restrict__ auxb,
              const int* __restrict__ uidx,   const int* __restrict__ midx,
              const u16* __restrict__ wt,     float* __restrict__ out)
{
    __shared__ __align__(16) u16 sX[TR * SXS];  // feats, later prior   [r][k]
    __shared__ __align__(16) u16 sH[TR * SHS];  // h, later d           [r][k]
    __shared__ int sN[TR];

    const int tid = threadIdx.x;
    const bool masked = (blockIdx.x < NBLK_M);
    const int p0 = (masked ? (int)blockIdx.x : ((int)blockIdx.x - NBLK_M)) * TR;
    const int* __restrict__ idx = masked ? midx : uidx;

    const int r   = tid & 63;
    const int n_r = idx[p0 + r];
    if (tid < TR) sN[tid] = n_r;

    // ---- gather x3d -> sX[r][c] bf16: all 32 loads in flight, then pack ----
    {
        const int cb = (tid >> 6) * 32;
        float v[32];
        #pragma unroll
        for (int j = 0; j < 32; ++j)
            v[j] = x3d[(size_t)(cb + j) * NVOX + n_r];
        #pragma unroll
        for (int ch = 0; ch < 4; ++ch) {
            bf16x8 pk;
            #pragma unroll
            for (int j = 0; j < 8; ++j) ((u16*)&pk)[j] = f2b(v[ch*8 + j]);
            *(bf16x8*)&sX[r * SXS + cb + ch*8] = pk;
        }
    }
    __syncthreads();

    const int m0   = (tid >> 6) * 16;  // wave's 16-row slice
    const int lane = tid & 63;
    const int q    = lane >> 4;        // quad
    const int n15  = lane & 15;
    const int kq   = q * 8;            // intra-chunk k offset for A/B frags

    if (masked) {
        // ---- GEMM1: feats[64x128] @ w1[128x64] -> LN -> leaky -> sH ----
        f32x4 acc[4];
        #pragma unroll
        for (int nt = 0; nt < 4; ++nt) {
            const float b = b1[nt*16 + n15];
            acc[nt] = (f32x4){b, b, b, b};
        }
        #pragma unroll
        for (int kc = 0; kc < 4; ++kc) {
            const int k0 = kc * 32;
            const bf16x8 a = *(const bf16x8*)&sX[(m0 + n15) * SXS + k0 + kq];
            #pragma unroll
            for (int nt = 0; nt < 4; ++nt) {
                const bf16x8 b = *(const bf16x8*)&wt[W1T_OFF + (nt*16 + n15)*CIN + k0 + kq];
                acc[nt] = __builtin_amdgcn_mfma_f32_16x16x32_bf16(a, b, acc[nt], 0, 0, 0);
            }
        }
        {
            float gv[4], ev[4];
            #pragma unroll
            for (int nt = 0; nt < 4; ++nt) { gv[nt] = lng[nt*16 + n15]; ev[nt] = lnb[nt*16 + n15]; }
            #pragma unroll
            for (int reg = 0; reg < 4; ++reg) {
                float s1 = acc[0][reg] + acc[1][reg] + acc[2][reg] + acc[3][reg];
                float s2 = acc[0][reg]*acc[0][reg] + acc[1][reg]*acc[1][reg]
                         + acc[2][reg]*acc[2][reg] + acc[3][reg]*acc[3][reg];
                #pragma unroll
                for (int m = 1; m <= 8; m <<= 1) {
                    s1 += __shfl_xor(s1, m, 64);
                    s2 += __shfl_xor(s2, m, 64);
                }
                const float mu  = s1 * (1.f/64.f);
                const float var = s2 * (1.f/64.f) - mu*mu;
                const float rs  = rsqrtf(var + 1e-5f);
                #pragma unroll
                for (int nt = 0; nt < 4; ++nt) {
                    float h = (acc[nt][reg] - mu) * rs * gv[nt] + ev[nt];
                    h = h > 0.f ? h : 0.01f*h;
                    sH[(m0 + q*4 + reg) * SHS + nt*16 + n15] = f2b(h);
                }
            }
        }
        wave_sync();

        // ---- GEMM2: h[64x64] @ w2[64x128] -> prior -> sX ----
        f32x4 acc2[8];
        #pragma unroll
        for (int nt = 0; nt < 8; ++nt) {
            const float b = bb2[nt*16 + n15];
            acc2[nt] = (f32x4){b, b, b, b};
        }
        #pragma unroll
        for (int kc = 0; kc < 2; ++kc) {
            const int k0 = kc * 32;
            const bf16x8 a = *(const bf16x8*)&sH[(m0 + n15) * SHS + k0 + kq];
            #pragma unroll
            for (int nt = 0; nt < 8; ++nt) {
                const bf16x8 b = *(const bf16x8*)&wt[W2T_OFF + (nt*16 + n15)*CHALF + k0 + kq];
                acc2[nt] = __builtin_amdgcn_mfma_f32_16x16x32_bf16(a, b, acc2[nt], 0, 0, 0);
            }
        }
        #pragma unroll
        for (int reg = 0; reg < 4; ++reg)
            #pragma unroll
            for (int nt = 0; nt < 8; ++nt)
                sX[(m0 + q*4 + reg) * SXS + nt*16 + n15] = f2b(acc2[nt][reg]);
        wave_sync();
    }

    // ---- SDB: row[64x128] @ sdb_w[128x64] -> leaky -> sH (= d) ----
    {
        f32x4 accd[4];
        #pragma unroll
        for (int nt = 0; nt < 4; ++nt) {
            const float b = sdbb[nt*16 + n15];
            accd[nt] = (f32x4){b, b, b, b};
        }
        #pragma unroll
        for (int kc = 0; kc < 4; ++kc) {
            const int k0 = kc * 32;
            const bf16x8 a = *(const bf16x8*)&sX[(m0 + n15) * SXS + k0 + kq];
            #pragma unroll
            for (int nt = 0; nt < 4; ++nt) {
                const bf16x8 b = *(const bf16x8*)&wt[SDBT_OFF + (nt*16 + n15)*CIN + k0 + kq];
                accd[nt] = __builtin_amdgcn_mfma_f32_16x16x32_bf16(a, b, accd[nt], 0, 0, 0);
            }
        }
        #pragma unroll
        for (int reg = 0; reg < 4; ++reg)
            #pragma unroll
            for (int nt = 0; nt < 4; ++nt) {
                float v = accd[nt][reg];
                v = v > 0.f ? v : 0.01f*v;
                sH[(m0 + q*4 + reg) * SHS + nt*16 + n15] = f2b(v);
            }
        wave_sync();
    }

    // ---- SSC: d[64x64] @ ssc_w[64x20] -> out[k*NVOX + n] ----
    {
        f32x4 accs[2];
        #pragma unroll
        for (int nt = 0; nt < 2; ++nt) {
            const int col = nt*16 + n15;
            const float b = (col < NCLS) ? sscb[col] : 0.f;
            accs[nt] = (f32x4){b, b, b, b};
        }
        #pragma unroll
        for (int kc = 0; kc < 2; ++kc) {
            const int k0 = kc * 32;
            const bf16x8 a = *(const bf16x8*)&sH[(m0 + n15) * SHS + k0 + kq];
            #pragma unroll
            for (int nt = 0; nt < 2; ++nt) {
                const bf16x8 b = *(const bf16x8*)&wt[SSCT_OFF + (nt*16 + n15)*CHALF + k0 + kq];
                accs[nt] = __builtin_amdgcn_mfma_f32_16x16x32_bf16(a, b, accs[nt], 0, 0, 0);
            }
        }
        int ng[4];
        #pragma unroll
        for (int reg = 0; reg < 4; ++reg) ng[reg] = sN[m0 + q*4 + reg];
        #pragma unroll
        for (int reg = 0; reg < 4; ++reg)
            out[(size_t)n15 * NVOX + ng[reg]] = accs[0][reg];
        if (n15 < 4) {
            #pragma unroll
            for (int reg = 0; reg < 4; ++reg)
                out[(size_t)(16 + n15) * NVOX + ng[reg]] = accs[1][reg];
        }
    }

    // ---- AUX (unmasked): feats[64x128] @ aux_w[128x20] -> out[20*NVOX + u*20 + k] ----
    if (!masked) {
        f32x4 acca[2];
        #pragma unroll
        for (int nt = 0; nt < 2; ++nt) {
            const int col = nt*16 + n15;
            const float b = (col < NCLS) ? auxb[col] : 0.f;
            acca[nt] = (f32x4){b, b, b, b};
        }
        #pragma unroll
        for (int kc = 0; kc < 4; ++kc) {
            const int k0 = kc * 32;
            const bf16x8 a = *(const bf16x8*)&sX[(m0 + n15) * SXS + k0 + kq];
            #pragma unroll
            for (int nt = 0; nt < 2; ++nt) {
                const bf16x8 b = *(const bf16x8*)&wt[AUXT_OFF + (nt*16 + n15)*CIN + k0 + kq];
                acca[nt] = __builtin_amdgcn_mfma_f32_16x16x32_bf16(a, b, acca[nt], 0, 0, 0);
            }
        }
        const size_t base = (size_t)NCLS * NVOX;
        #pragma unroll
        for (int reg = 0; reg < 4; ++reg) {
            const int u = p0 + m0 + q*4 + reg;
            out[base + (size_t)u * NCLS + n15] = acca[0][reg];
            if (n15 < 4)
                out[base + (size_t)u * NCLS + 16 + n15] = acca[1][reg];
        }
    }
}

extern "C" void kernel_launch(void* const* d_in, const int* in_sizes, int n_in,
                              void* d_out, int out_size, void* d_ws, size_t ws_size,
                              hipStream_t stream) {
    const float* x3d  = (const float*)d_in[0];
    const float* w1   = (const float*)d_in[1];
    const float* b1   = (const float*)d_in[2];
    const float* lng  = (const float*)d_in[3];
    const float* lnb  = (const float*)d_in[4];
    const float* w2   = (const float*)d_in[5];
    const float* bb2  = (const float*)d_in[6];
    const float* sdbw = (const float*)d_in[7];
    const float* sdbb = (const float*)d_in[8];
    const float* sscw = (const float*)d_in[9];
    const float* sscb = (const float*)d_in[10];
    const float* auxw = (const float*)d_in[11];
    const float* auxb = (const float*)d_in[12];
    const int*   uidx = (const int*)d_in[13];
    const int*   midx = (const int*)d_in[14];
    float* out = (float*)d_out;
    u16*   wt  = (u16*)d_ws;

    hipLaunchKernelGGL(prep_weights, dim3(64), dim3(256), 0, stream,
                       w1, w2, sdbw, sscw, auxw, wt);
    hipLaunchKernelGGL(sgn_mfma, dim3(NBLK_M + NBLK_U), dim3(256), 0, stream,
                       x3d, b1, lng, lnb, bb2, sdbb, sscb, auxb,
                       uidx, midx, wt, out);
}

// Round 6
// 265.011 us; speedup vs baseline: 1.2013x; 1.2013x over previous
//
#include <hip/hip_runtime.h>
#include <hip/hip_bf16.h>

// SGNHeadLSS — round 6.
// r5 post-mortem: (256,6) VGPR cap 85 + hoisted v[32] => scratch spill
// (VGPR 40, WRITE 46->84MB) — regressed. Reverted to (256,3).
// r4 model: all pipes idle; cost is VMEM instruction processing of
// DIVERGENT loads (60 wt B-frag loads/wave, 16 cache lines each).
// Fix: weights pre-swizzled into MFMA fragment order in d_ws, staged
// per-phase into a 16KB LDS buffer with coalesced uint4 copies; B-frags
// become conflict-free ds_read_b128 at chunk_base + lane*16.
// Compute math identical to r4 (passed, absmax 0.023).

#define NVOX 262144
#define NU   65536
#define NM   196608
#define CIN  128
#define CHALF 64
#define NCLS 20
#define TR   64
#define NBLK_M (NM / TR) // 3072
#define NBLK_U (NU / TR) // 1024

#define SXS 136   // sX row stride in u16 (272B, 16B-aligned)
#define SHS 72    // sH row stride in u16 (144B, 16B-aligned)

// ws layout (u16 units), fragment order: [nt][kc][lane]*8
#define W1F  0       // nt4 kc4  -> 8192
#define W2F  8192    // nt8 kc2  -> 8192
#define SDBF 16384   // nt4 kc4  -> 8192
#define SSCF 24576   // nt2 kc2  -> 2048
#define AUXF 26624   // nt2 kc4  -> 4096
#define WS_TOT 30720 // 61440 bytes

typedef unsigned short u16;
typedef short    bf16x8 __attribute__((ext_vector_type(8)));
typedef float    f32x4  __attribute__((ext_vector_type(4)));

__device__ __forceinline__ u16 f2b(float f) {
    __hip_bfloat16 h = __float2bfloat16(f);
    return *(u16*)&h;
}

// B-frag layout: lane=q*16+n15 holds B[k=kc*32+q*8+j][n=nt*16+n15], j=0..7
__global__ void prep_weights(const float* __restrict__ w1,  const float* __restrict__ w2,
                             const float* __restrict__ sdbw,const float* __restrict__ sscw,
                             const float* __restrict__ auxw,u16* __restrict__ ws) {
    int i = blockIdx.x * blockDim.x + threadIdx.x;
    const int stride = gridDim.x * blockDim.x;
    for (; i < WS_TOT; i += stride) {
        float v;
        if (i < W2F) {                      // w1^frag: N=64, K=128
            int t = i, j = t & 7, lane = (t >> 3) & 63, kc = (t >> 9) & 3, nt = t >> 11;
            int k = kc*32 + (lane >> 4)*8 + j, n = nt*16 + (lane & 15);
            v = w1[k*CHALF + n];
        } else if (i < SDBF) {              // w2^frag: N=128, K=64
            int t = i - W2F, j = t & 7, lane = (t >> 3) & 63, kc = (t >> 9) & 1, nt = t >> 10;
            int k = kc*32 + (lane >> 4)*8 + j, n = nt*16 + (lane & 15);
            v = w2[k*CIN + n];
        } else if (i < SSCF) {              // sdb^frag: N=64, K=128
            int t = i - SDBF, j = t & 7, lane = (t >> 3) & 63, kc = (t >> 9) & 3, nt = t >> 11;
            int k = kc*32 + (lane >> 4)*8 + j, n = nt*16 + (lane & 15);
            v = sdbw[k*CHALF + n];
        } else if (i < AUXF) {              // ssc^frag: N=32(pad), K=64
            int t = i - SSCF, j = t & 7, lane = (t >> 3) & 63, kc = (t >> 9) & 1, nt = t >> 10;
            int k = kc*32 + (lane >> 4)*8 + j, n = nt*16 + (lane & 15);
            v = (n < NCLS) ? sscw[k*NCLS + n] : 0.f;
        } else {                            // aux^frag: N=32(pad), K=128
            int t = i - AUXF, j = t & 7, lane = (t >> 3) & 63, kc = (t >> 9) & 3, nt = t >> 11;
            int k = kc*32 + (lane >> 4)*8 + j, n = nt*16 + (lane & 15);
            v = (n < NCLS) ? auxw[k*NCLS + n] : 0.f;
        }
        ws[i] = f2b(v);
    }
}

__global__ __launch_bounds__(256, 3)
void sgn_mfma(const float* __restrict__ x3d,
              const float* __restrict__ b1,   const float* __restrict__ lng,
              const float* __restrict__ lnb,  const float* __restrict__ bb2,
              const float* __restrict__ sdbb, const float* __restrict__ sscb,
              const float* __restrict__ auxb,
              const int* __restrict__ uidx,   const int* __restrict__ midx,
              const u16* __restrict__ wt,     float* __restrict__ out)
{
    __shared__ __align__(16) u16 sX[TR * SXS];   // feats / prior  [r][k]
    __shared__ __align__(16) u16 sH[TR * SHS];   // h / d          [r][k]
    __shared__ __align__(16) u16 wbuf[8192];     // staged weight frags (16 KB)
    __shared__ int sN[TR];

    const int tid = threadIdx.x;
    const bool masked = (blockIdx.x < NBLK_M);
    const int p0 = (masked ? (int)blockIdx.x : ((int)blockIdx.x - NBLK_M)) * TR;
    const int* __restrict__ idx = masked ? midx : uidx;

    const int r   = tid & 63;
    const int n_r = idx[p0 + r];
    if (tid < TR) sN[tid] = n_r;

    // ---- gather x3d -> registers (all 32 loads in flight) ----
    const int cb = (tid >> 6) * 32;
    float v[32];
    #pragma unroll
    for (int j = 0; j < 32; ++j)
        v[j] = x3d[(size_t)(cb + j) * NVOX + n_r];

    // ---- stage phase-1 weights (coalesced): masked->w1, unmasked->sdb ----
    {
        const uint4* src = (const uint4*)(wt + (masked ? W1F : SDBF));
        #pragma unroll
        for (int t = 0; t < 4; ++t)
            ((uint4*)wbuf)[tid + t*256] = src[tid + t*256];
    }

    // ---- pack gather -> sX[r][c] bf16 ----
    #pragma unroll
    for (int ch = 0; ch < 4; ++ch) {
        bf16x8 pk;
        #pragma unroll
        for (int j = 0; j < 8; ++j) ((u16*)&pk)[j] = f2b(v[ch*8 + j]);
        *(bf16x8*)&sX[r * SXS + cb + ch*8] = pk;
    }
    __syncthreads();

    const int m0   = (tid >> 6) * 16;  // wave's 16-row slice
    const int lane = tid & 63;
    const int q    = lane >> 4;
    const int n15  = lane & 15;
    const int kq   = q * 8;

    if (masked) {
        // ---- GEMM1: feats[64x128] @ w1 -> LN -> leaky -> sH ----
        f32x4 acc[4];
        #pragma unroll
        for (int nt = 0; nt < 4; ++nt) {
            const float b = b1[nt*16 + n15];
            acc[nt] = (f32x4){b, b, b, b};
        }
        #pragma unroll
        for (int kc = 0; kc < 4; ++kc) {
            const bf16x8 a = *(const bf16x8*)&sX[(m0 + n15) * SXS + kc*32 + kq];
            #pragma unroll
            for (int nt = 0; nt < 4; ++nt) {
                const bf16x8 b = *(const bf16x8*)&wbuf[((nt*4 + kc)*64 + lane)*8];
                acc[nt] = __builtin_amdgcn_mfma_f32_16x16x32_bf16(a, b, acc[nt], 0, 0, 0);
            }
        }
        {
            float gv[4], ev[4];
            #pragma unroll
            for (int nt = 0; nt < 4; ++nt) { gv[nt] = lng[nt*16 + n15]; ev[nt] = lnb[nt*16 + n15]; }
            #pragma unroll
            for (int reg = 0; reg < 4; ++reg) {
                float s1 = acc[0][reg] + acc[1][reg] + acc[2][reg] + acc[3][reg];
                float s2 = acc[0][reg]*acc[0][reg] + acc[1][reg]*acc[1][reg]
                         + acc[2][reg]*acc[2][reg] + acc[3][reg]*acc[3][reg];
                #pragma unroll
                for (int m = 1; m <= 8; m <<= 1) {
                    s1 += __shfl_xor(s1, m, 64);
                    s2 += __shfl_xor(s2, m, 64);
                }
                const float mu  = s1 * (1.f/64.f);
                const float var = s2 * (1.f/64.f) - mu*mu;
                const float rs  = rsqrtf(var + 1e-5f);
                #pragma unroll
                for (int nt = 0; nt < 4; ++nt) {
                    float h = (acc[nt][reg] - mu) * rs * gv[nt] + ev[nt];
                    h = h > 0.f ? h : 0.01f*h;
                    sH[(m0 + q*4 + reg) * SHS + nt*16 + n15] = f2b(h);
                }
            }
        }
        __syncthreads();                      // wbuf free + sH visible

        // ---- stage w2 frags ----
        #pragma unroll
        for (int t = 0; t < 4; ++t)
            ((uint4*)wbuf)[tid + t*256] = ((const uint4*)(wt + W2F))[tid + t*256];
        __syncthreads();

        // ---- GEMM2: h[64x64] @ w2 -> prior -> sX ----
        f32x4 acc2[8];
        #pragma unroll
        for (int nt = 0; nt < 8; ++nt) {
            const float b = bb2[nt*16 + n15];
            acc2[nt] = (f32x4){b, b, b, b};
        }
        #pragma unroll
        for (int kc = 0; kc < 2; ++kc) {
            const bf16x8 a = *(const bf16x8*)&sH[(m0 + n15) * SHS + kc*32 + kq];
            #pragma unroll
            for (int nt = 0; nt < 8; ++nt) {
                const bf16x8 b = *(const bf16x8*)&wbuf[((nt*2 + kc)*64 + lane)*8];
                acc2[nt] = __builtin_amdgcn_mfma_f32_16x16x32_bf16(a, b, acc2[nt], 0, 0, 0);
            }
        }
        #pragma unroll
        for (int reg = 0; reg < 4; ++reg)
            #pragma unroll
            for (int nt = 0; nt < 8; ++nt)
                sX[(m0 + q*4 + reg) * SXS + nt*16 + n15] = f2b(acc2[nt][reg]);
        __syncthreads();                      // wbuf free + sX visible

        // ---- stage sdb frags ----
        #pragma unroll
        for (int t = 0; t < 4; ++t)
            ((uint4*)wbuf)[tid + t*256] = ((const uint4*)(wt + SDBF))[tid + t*256];
        __syncthreads();
    }

    // ---- SDB: row[64x128] @ sdb_w -> leaky -> sH (= d) ----
    {
        f32x4 accd[4];
        #pragma unroll
        for (int nt = 0; nt < 4; ++nt) {
            const float b = sdbb[nt*16 + n15];
            accd[nt] = (f32x4){b, b, b, b};
        }
        #pragma unroll
        for (int kc = 0; kc < 4; ++kc) {
            const bf16x8 a = *(const bf16x8*)&sX[(m0 + n15) * SXS + kc*32 + kq];
            #pragma unroll
            for (int nt = 0; nt < 4; ++nt) {
                const bf16x8 b = *(const bf16x8*)&wbuf[((nt*4 + kc)*64 + lane)*8];
                accd[nt] = __builtin_amdgcn_mfma_f32_16x16x32_bf16(a, b, accd[nt], 0, 0, 0);
            }
        }
        #pragma unroll
        for (int reg = 0; reg < 4; ++reg)
            #pragma unroll
            for (int nt = 0; nt < 4; ++nt) {
                float vv = accd[nt][reg];
                vv = vv > 0.f ? vv : 0.01f*vv;
                sH[(m0 + q*4 + reg) * SHS + nt*16 + n15] = f2b(vv);
            }
    }
    __syncthreads();                          // wbuf free + sH visible

    // ---- stage ssc (+aux for unmasked) frags ----
    if (masked) {
        if (tid < 256) ((uint4*)wbuf)[tid] = ((const uint4*)(wt + SSCF))[tid];
    } else {
        #pragma unroll
        for (int t = 0; t < 3; ++t)
            ((uint4*)wbuf)[tid + t*256] = ((const uint4*)(wt + SSCF))[tid + t*256];
    }
    __syncthreads();

    // ---- SSC: d[64x64] @ ssc_w[64x20] -> out[k*NVOX + n] ----
    {
        f32x4 accs[2];
        #pragma unroll
        for (int nt = 0; nt < 2; ++nt) {
            const int col = nt*16 + n15;
            const float b = (col < NCLS) ? sscb[col] : 0.f;
            accs[nt] = (f32x4){b, b, b, b};
        }
        #pragma unroll
        for (int kc = 0; kc < 2; ++kc) {
            const bf16x8 a = *(const bf16x8*)&sH[(m0 + n15) * SHS + kc*32 + kq];
            #pragma unroll
            for (int nt = 0; nt < 2; ++nt) {
                const bf16x8 b = *(const bf16x8*)&wbuf[((nt*2 + kc)*64 + lane)*8];
                accs[nt] = __builtin_amdgcn_mfma_f32_16x16x32_bf16(a, b, accs[nt], 0, 0, 0);
            }
        }
        int ng[4];
        #pragma unroll
        for (int reg = 0; reg < 4; ++reg) ng[reg] = sN[m0 + q*4 + reg];
        #pragma unroll
        for (int reg = 0; reg < 4; ++reg)
            out[(size_t)n15 * NVOX + ng[reg]] = accs[0][reg];
        if (n15 < 4) {
            #pragma unroll
            for (int reg = 0; reg < 4; ++reg)
                out[(size_t)(16 + n15) * NVOX + ng[reg]] = accs[1][reg];
        }
    }

    // ---- AUX (unmasked): feats @ aux_w -> out[20*NVOX + u*20 + k] ----
    if (!masked) {
        f32x4 acca[2];
        #pragma unroll
        for (int nt = 0; nt < 2; ++nt) {
            const int col = nt*16 + n15;
            const float b = (col < NCLS) ? auxb[col] : 0.f;
            acca[nt] = (f32x4){b, b, b, b};
        }
        #pragma unroll
        for (int kc = 0; kc < 4; ++kc) {
            const bf16x8 a = *(const bf16x8*)&sX[(m0 + n15) * SXS + kc*32 + kq];
            #pragma unroll
            for (int nt = 0; nt < 2; ++nt) {
                const bf16x8 b = *(const bf16x8*)&wbuf[2048 + ((nt*4 + kc)*64 + lane)*8];
                acca[nt] = __builtin_amdgcn_mfma_f32_16x16x32_bf16(a, b, acca[nt], 0, 0, 0);
            }
        }
        const size_t base = (size_t)NCLS * NVOX;
        #pragma unroll
        for (int reg = 0; reg < 4; ++reg) {
            const int u = p0 + m0 + q*4 + reg;
            out[base + (size_t)u * NCLS + n15] = acca[0][reg];
            if (n15 < 4)
                out[base + (size_t)u * NCLS + 16 + n15] = acca[1][reg];
        }
    }
}

extern "C" void kernel_launch(void* const* d_in, const int* in_sizes, int n_in,
                              void* d_out, int out_size, void* d_ws, size_t ws_size,
                              hipStream_t stream) {
    const float* x3d  = (const float*)d_in[0];
    const float* w1   = (const float*)d_in[1];
    const float* b1   = (const float*)d_in[2];
    const float* lng  = (const float*)d_in[3];
    const float* lnb  = (const float*)d_in[4];
    const float* w2   = (const float*)d_in[5];
    const float* bb2  = (const float*)d_in[6];
    const float* sdbw = (const float*)d_in[7];
    const float* sdbb = (const float*)d_in[8];
    const float* sscw = (const float*)d_in[9];
    const float* sscb = (const float*)d_in[10];
    const float* auxw = (const float*)d_in[11];
    const float* auxb = (const float*)d_in[12];
    const int*   uidx = (const int*)d_in[13];
    const int*   midx = (const int*)d_in[14];
    float* out = (float*)d_out;
    u16*   wt  = (u16*)d_ws;

    hipLaunchKernelGGL(prep_weights, dim3(64), dim3(256), 0, stream,
                       w1, w2, sdbw, sscw, auxw, wt);
    hipLaunchKernelGGL(sgn_mfma, dim3(NBLK_M + NBLK_U), dim3(256), 0, stream,
                       x3d, b1, lng, lnb, bb2, sdbb, sscb, auxb,
                       uidx, midx, wt, out);
}